// Round 17
// baseline (166.856 us; speedup 1.0000x reference)
//
#include <hip/hip_runtime.h>

#define N_NODES 100000
#define N_EDGES 1600000
#define IN_F 64
#define HID 128
#define HID2 64
#define NCLS 10

// fixed-stride padded CSR: 64 slots per node (max Poisson-16 degree ~45)
#define SEG 64

// two-level binning: 256 sub-buckets of 391 nodes (100KB csr window each)
#define NBUCK 256
#define SUBR 391                       // ceil(100000/256)
#define CAP2 7000                      // mean 6250, ~9.5 sigma margin
#define EBA 1600                       // edges per binA block (1000 blocks)

typedef __attribute__((ext_vector_type(8))) short bfrag;
typedef __attribute__((ext_vector_type(4))) float f32x4;

// ---- RNE float->bf16 ----
__device__ __forceinline__ unsigned short bf_rne(float f) {
  unsigned int u = __float_as_uint(f);
  u += 0x7fffu + ((u >> 16) & 1u);
  return (unsigned short)(u >> 16);
}

// ---------------- cast x -> bf16 (8 floats / thread) ----------------
__global__ __launch_bounds__(256) void cast_k(const float* __restrict__ x,
                                              unsigned short* __restrict__ xb) {
  int i = blockIdx.x * blockDim.x + threadIdx.x;   // 8-float unit
  const float4* xf4 = (const float4*)x;
  float4 a = xf4[2 * i];
  float4 b = xf4[2 * i + 1];
  ushort4 o0, o1;
  o0.x = bf_rne(a.x); o0.y = bf_rne(a.y); o0.z = bf_rne(a.z); o0.w = bf_rne(a.w);
  o1.x = bf_rne(b.x); o1.y = bf_rne(b.y); o1.z = bf_rne(b.z); o1.w = bf_rne(b.w);
  ushort4* ob = (ushort4*)xb;
  ob[2 * i] = o0;
  ob[2 * i + 1] = o1;
}

// ---------------- W1/W2 -> bf16 transposed [out][k] (once) ----------------
__global__ __launch_bounds__(256) void wtrans_k(const float* __restrict__ W1,
                                                const float* __restrict__ W2,
                                                unsigned short* __restrict__ W1t,
                                                unsigned short* __restrict__ W2t) {
  int i = blockIdx.x * 256 + threadIdx.x;          // 0 .. 16383
  if (i < IN_F * HID) {                            // W1t[j][k] = W1[k][j]
    int j = i >> 6, k = i & 63;                    // j<128, k<64
    W1t[i] = bf_rne(W1[k * HID + j]);
  } else {
    int i2 = i - IN_F * HID;                       // W2t[j][k] = W2[k][j]
    int j = i2 >> 7, k = i2 & 127;                 // j<64, k<128
    W2t[i2] = bf_rne(W2[k * HID2 + j]);
  }
}

// ---- binA: bin edges into 256 buckets as packed (local<<17|src) u32 ----
__global__ __launch_bounds__(256) void binA_k(const int* __restrict__ row,
                                              const int* __restrict__ col,
                                              int* __restrict__ bcnt,
                                              unsigned int* __restrict__ pairs) {
  __shared__ int hcnt[NBUCK];
  __shared__ int hbase[NBUCK];
  int t = threadIdx.x;
  hcnt[t] = 0;
  __syncthreads();
  int e0 = blockIdx.x * EBA;
  int e1 = e0 + EBA;
  for (int e = e0 + t; e < e1; e += 256) {
    int b = col[e] / SUBR;
    atomicAdd(&hcnt[b], 1);
  }
  __syncthreads();
  hbase[t] = atomicAdd(&bcnt[t], hcnt[t]);
  hcnt[t] = 0;
  __syncthreads();
  for (int e = e0 + t; e < e1; e += 256) {
    int dst = col[e];
    int src = row[e];
    int b = dst / SUBR;
    int pos = hbase[b] + atomicAdd(&hcnt[b], 1);
    pairs[(size_t)b * CAP2 + pos] =
        ((unsigned)(dst - b * SUBR) << 17) | (unsigned)src;
  }
}

// ---- binB: one block per bucket; LDS cursors; 100KB private csr window ----
// Zero-fills slots d..cons (cons = 32 or ceil16(d)) so the gather can read
// the first 32 slots (and any tail units) unconditionally.
__global__ __launch_bounds__(512) void binB_k(const unsigned int* __restrict__ pairs,
                                              const int* __restrict__ bcnt,
                                              int* __restrict__ cursors,
                                              int* __restrict__ csr_src) {
  __shared__ int cur[SUBR];
  int b = blockIdx.x;
  int t = threadIdx.x;
  int lo = b * SUBR;
  for (int i = t; i < SUBR; i += 512) cur[i] = 0;
  __syncthreads();
  int cnt = bcnt[b];
  const unsigned int* bp = pairs + (size_t)b * CAP2;
  for (int i = t; i < cnt; i += 512) {
    unsigned w = bp[i];
    int local = w >> 17;
    int src = (int)(w & 0x1ffffu);
    int pos = atomicAdd(&cur[local], 1);
    if (pos < SEG) csr_src[(size_t)(lo + local) * SEG + pos] = src;
  }
  __syncthreads();
  for (int i = t; i < SUBR; i += 512) {
    int n = lo + i;
    if (n < N_NODES) {
      int d = cur[i];
      if (d > SEG) d = SEG;
      cursors[n] = n * SEG + d;
      int cons = d <= 32 ? 32 : ((d + 15) & ~15);
      for (int q = d; q < cons; q++) csr_src[(size_t)n * SEG + q] = 0;
    }
  }
}

// ---------- per-node bf16 gather (TLP version: no LDS, no barriers) ----------
// Row = 64 bf16 = 128 B. Lane = eg(0..3 edge-subgroup) x fc(0..15 chunk).
// Slots [0,32) always initialized (binB); pad slots = row0, subtracted.
// After xor-reduce 16/32 ALL lanes hold the node's sum for chunk fc.
__device__ __forceinline__ float4 gather_node(const uint2* __restrict__ vb,
                                              const int4* __restrict__ csr4,
                                              int n, int d, int eg, int fc,
                                              float zx, float zy, float zz,
                                              float zw) {
  float ax = 0.f, ay = 0.f, az = 0.f, aw = 0.f;
  int s4 = n * 16;                           // 16 int4 units per SEG
  int4 ia = csr4[s4 + eg];
  int4 ib = csr4[s4 + 4 + eg];
  uint2 r0 = vb[(size_t)(unsigned)ia.x * 16 + fc];
  uint2 r1 = vb[(size_t)(unsigned)ia.y * 16 + fc];
  uint2 r2 = vb[(size_t)(unsigned)ia.z * 16 + fc];
  uint2 r3 = vb[(size_t)(unsigned)ia.w * 16 + fc];
  uint2 r4 = vb[(size_t)(unsigned)ib.x * 16 + fc];
  uint2 r5 = vb[(size_t)(unsigned)ib.y * 16 + fc];
  uint2 r6 = vb[(size_t)(unsigned)ib.z * 16 + fc];
  uint2 r7 = vb[(size_t)(unsigned)ib.w * 16 + fc];
#define ACC1(r)                                                     \
  {                                                                 \
    ax += __uint_as_float((r).x << 16);                             \
    ay += __uint_as_float((r).x & 0xffff0000u);                     \
    az += __uint_as_float((r).y << 16);                             \
    aw += __uint_as_float((r).y & 0xffff0000u);                     \
  }
  ACC1(r0) ACC1(r1) ACC1(r2) ACC1(r3) ACC1(r4) ACC1(r5) ACC1(r6) ACC1(r7)
  int cons = 32;
  if (d > 32) {                              // rare tail (P ~ 2e-4)
    cons = (d + 15) & ~15;
    for (int p = n * SEG + 32; p < n * SEG + cons; p += 16) {
      int4 it = csr4[(p >> 2) + eg];
      uint2 t0 = vb[(size_t)(unsigned)it.x * 16 + fc];
      uint2 t1 = vb[(size_t)(unsigned)it.y * 16 + fc];
      uint2 t2 = vb[(size_t)(unsigned)it.z * 16 + fc];
      uint2 t3 = vb[(size_t)(unsigned)it.w * 16 + fc];
      ACC1(t0) ACC1(t1) ACC1(t2) ACC1(t3)
    }
  }
#undef ACC1
  ax += __shfl_xor(ax, 16); ay += __shfl_xor(ay, 16);
  az += __shfl_xor(az, 16); aw += __shfl_xor(aw, 16);
  ax += __shfl_xor(ax, 32); ay += __shfl_xor(ay, 32);
  az += __shfl_xor(az, 32); aw += __shfl_xor(aw, 32);
  float pc = (float)(cons - d);
  return make_float4(ax - pc * zx, ay - pc * zy, az - pc * zz, aw - pc * zw);
}

// ---------- gather1: xm[n] = bf16(mean of xb rows) ----------
// 256 thr = 4 waves x 4 nodes; no LDS/barriers -> 8 waves/SIMD residency.
__global__ __launch_bounds__(256) void gather1_k(
    const unsigned short* __restrict__ xb, const int* __restrict__ cursors,
    const int* __restrict__ csr_src, unsigned short* __restrict__ xm) {
  int t = threadIdx.x;
  int lane = t & 63;
  int eg = lane >> 4;
  int fc = lane & 15;
  int n0 = (blockIdx.x * 4 + (t >> 6)) * 4;
  const uint2* vb = (const uint2*)xb;
  const int4* csr4 = (const int4*)csr_src;
  uint2 z = vb[fc];
  float zx = __uint_as_float(z.x << 16);
  float zy = __uint_as_float(z.x & 0xffff0000u);
  float zz = __uint_as_float(z.y << 16);
  float zw = __uint_as_float(z.y & 0xffff0000u);
  for (int i = 0; i < 4; i++) {
    int n = n0 + i;
    int d = cursors[n] - n * SEG;
    float4 a = gather_node(vb, csr4, n, d, eg, fc, zx, zy, zz, zw);
    if (eg == 0) {
      float inv = 1.0f / (d < 1 ? 1.0f : (float)d);
      ushort4 o;
      o.x = bf_rne(a.x * inv); o.y = bf_rne(a.y * inv);
      o.z = bf_rne(a.z * inv); o.w = bf_rne(a.w * inv);
      *(ushort4*)&xm[(size_t)n * IN_F + fc * 4] = o;
    }
  }
}

// ---------- gather2: hm[n] = bf16(relu(mean of g rows + b2)) ----------
__global__ __launch_bounds__(256) void gather2_k(
    const unsigned short* __restrict__ g, const int* __restrict__ cursors,
    const int* __restrict__ csr_src, const float* __restrict__ b2,
    unsigned short* __restrict__ hm) {
  int t = threadIdx.x;
  int lane = t & 63;
  int eg = lane >> 4;
  int fc = lane & 15;
  int n0 = (blockIdx.x * 4 + (t >> 6)) * 4;
  const uint2* vb = (const uint2*)g;
  const int4* csr4 = (const int4*)csr_src;
  uint2 z = vb[fc];
  float zx = __uint_as_float(z.x << 16);
  float zy = __uint_as_float(z.x & 0xffff0000u);
  float zz = __uint_as_float(z.y << 16);
  float zw = __uint_as_float(z.y & 0xffff0000u);
  const float4* b2f4 = (const float4*)b2;
  float4 bb = b2f4[fc];
  for (int i = 0; i < 4; i++) {
    int n = n0 + i;
    int d = cursors[n] - n * SEG;
    float4 a = gather_node(vb, csr4, n, d, eg, fc, zx, zy, zz, zw);
    if (eg == 0) {
      float inv = 1.0f / (d < 1 ? 1.0f : (float)d);
      float vx = a.x * inv + bb.x;
      float vy = a.y * inv + bb.y;
      float vz = a.z * inv + bb.z;
      float vw = a.w * inv + bb.w;
      ushort4 o;
      o.x = bf_rne(vx > 0.0f ? vx : 0.0f);
      o.y = bf_rne(vy > 0.0f ? vy : 0.0f);
      o.z = bf_rne(vz > 0.0f ? vz : 0.0f);
      o.w = bf_rne(vw > 0.0f ? vw : 0.0f);
      *(ushort4*)&hm[(size_t)n * HID2 + fc * 4] = o;
    }
  }
}

// ---------- mm12: dense MFMA, g = bf16(relu(xm@W1+b1) @ W2) ----------
// 32 nodes/block, 512 thr (8 waves); xm tile staged coalesced into LDS.
#define NB1 32
#define XS_S 72
#define HS_S 136
__global__ __launch_bounds__(512) void mm12_k(
    const unsigned short* __restrict__ xm, const unsigned short* __restrict__ W1t,
    const float* __restrict__ b1, const unsigned short* __restrict__ W2t,
    unsigned short* __restrict__ g) {
  __shared__ unsigned short xsb[NB1 * XS_S];    // 4.5 KB
  __shared__ unsigned short hsb[NB1 * HS_S];    // 8.5 KB
  int t = threadIdx.x;
  int node0 = blockIdx.x * NB1;
  // stage xm tile: 32 rows x 16 ushort4 units = 512 units, one per thread
  {
    int r = t >> 4, u = t & 15;
    *(ushort4*)&xsb[r * XS_S + u * 4] =
        ((const ushort4*)xm)[(size_t)(node0 + r) * (IN_F / 4) + u];
  }
  __syncthreads();
  int wave = t >> 6;
  int lane = t & 63;
  int lr = lane & 15;
  int kb = lane >> 4;
  // ---- mm1 (MFMA): hsb = relu(xsb @ W1 + b1); wave w -> col-tile c=w ----
  {
    int col = wave * 16 + lr;
    bfrag wf0 = *(const bfrag*)&W1t[col * IN_F + kb * 8];
    bfrag wf1 = *(const bfrag*)&W1t[col * IN_F + 32 + kb * 8];
    float bb = b1[col];
#pragma unroll
    for (int m = 0; m < 2; m++) {
      f32x4 acc = {0.f, 0.f, 0.f, 0.f};
      bfrag a0 = *(const bfrag*)&xsb[(m * 16 + lr) * XS_S + kb * 8];
      bfrag a1 = *(const bfrag*)&xsb[(m * 16 + lr) * XS_S + 32 + kb * 8];
      acc = __builtin_amdgcn_mfma_f32_16x16x32_bf16(a0, wf0, acc, 0, 0, 0);
      acc = __builtin_amdgcn_mfma_f32_16x16x32_bf16(a1, wf1, acc, 0, 0, 0);
#pragma unroll
      for (int q = 0; q < 4; q++) {
        int r = m * 16 + kb * 4 + q;
        float v = acc[q] + bb;
        hsb[r * HS_S + col] = bf_rne(v > 0.0f ? v : 0.0f);
      }
    }
  }
  __syncthreads();
  // ---- mm2 (MFMA): g = bf16(hsb @ W2); wave w -> (m=w>>2, c=w&3) ----
  {
    int m = wave >> 2;
    int col = (wave & 3) * 16 + lr;
    f32x4 acc = {0.f, 0.f, 0.f, 0.f};
#pragma unroll
    for (int s = 0; s < 4; s++) {
      bfrag af = *(const bfrag*)&hsb[(m * 16 + lr) * HS_S + s * 32 + kb * 8];
      bfrag bf = *(const bfrag*)&W2t[col * HID + s * 32 + kb * 8];
      acc = __builtin_amdgcn_mfma_f32_16x16x32_bf16(af, bf, acc, 0, 0, 0);
    }
#pragma unroll
    for (int q = 0; q < 4; q++) {
      int r = m * 16 + kb * 4 + q;
      g[(size_t)(node0 + r) * HID2 + col] = bf_rne(acc[q]);
    }
  }
}

// ---------- head: out = hm @ W3 + b3 ----------
// 25 nodes/block, 256 thr; hm tile -> LDS fp32; 250 thr compute 10 cls each.
#define NBH3 25
__global__ __launch_bounds__(256) void head_k(
    const unsigned short* __restrict__ hm, const float* __restrict__ W3,
    const float* __restrict__ b3, float* __restrict__ out) {
  __shared__ float W3l[HID2 * NCLS];       // 2.5 KB
  __shared__ float hsl[NBH3][HID2 + 4];    // 6.8 KB
  int t = threadIdx.x;
  for (int i = t; i < HID2 * NCLS; i += 256) W3l[i] = W3[i];
  int node0 = blockIdx.x * NBH3;
  for (int u = t; u < NBH3 * (HID2 / 4); u += 256) {
    int r = u >> 4, c = u & 15;
    ushort4 v = ((const ushort4*)hm)[(size_t)(node0 + r) * (HID2 / 4) + c];
    hsl[r][c * 4 + 0] = __uint_as_float((unsigned)v.x << 16);
    hsl[r][c * 4 + 1] = __uint_as_float((unsigned)v.y << 16);
    hsl[r][c * 4 + 2] = __uint_as_float((unsigned)v.z << 16);
    hsl[r][c * 4 + 3] = __uint_as_float((unsigned)v.w << 16);
  }
  __syncthreads();
  if (t < NBH3 * NCLS) {
    int n = t / NCLS;
    int c = t - n * NCLS;
    float a = b3[c];
    for (int k = 0; k < HID2; k++) a += hsl[n][k] * W3l[k * NCLS + c];
    out[(size_t)(node0 + n) * NCLS + c] = a;
  }
}

extern "C" void kernel_launch(void* const* d_in, const int* in_sizes, int n_in,
                              void* d_out, int out_size, void* d_ws, size_t ws_size,
                              hipStream_t stream) {
  const float* x  = (const float*)d_in[0];
  const int*   ei = (const int*)d_in[1];
  const int*   row = ei;
  const int*   col = ei + N_EDGES;
  const float* W1 = (const float*)d_in[3];
  const float* b1 = (const float*)d_in[4];
  const float* W2 = (const float*)d_in[5];
  const float* b2 = (const float*)d_in[6];
  const float* W3 = (const float*)d_in[7];
  const float* b3 = (const float*)d_in[8];
  float* out = (float*)d_out;

  char* ws = (char*)d_ws;
  int*            cursors = (int*)ws;                            // 400 KB
  int*            bcnt    = (int*)(ws + (512 << 10));            // 1 KB
  unsigned short* W1t     = (unsigned short*)(ws + (520 << 10)); // 16 KB
  unsigned short* W2t     = (unsigned short*)(ws + (552 << 10)); // 16 KB
  int*            csr_src = (int*)(ws + (1 << 20));              // 25.6 MB
  unsigned int*   pairs   = (unsigned int*)(ws + (28 << 20));    // 7.2 MB
  unsigned short* xb      = (unsigned short*)(ws + (36 << 20));  // 12.8 MB
  unsigned short* g       = (unsigned short*)(ws + (49 << 20));  // 12.8 MB
  unsigned short* xm      = (unsigned short*)(ws + (62 << 20));  // 12.8 MB
  unsigned short* hm      = xm;  // aliased: xm dead after mm12_k, hm written after

  // ---- prep: bf16 cast + W transpose + two-level binned CSR build ----
  (void)hipMemsetAsync(bcnt, 0, NBUCK * sizeof(int), stream);
  wtrans_k<<<(IN_F * HID + HID * HID2) / 256, 256, 0, stream>>>(W1, W2, W1t, W2t);
  cast_k<<<N_NODES * IN_F / 8 / 256, 256, 0, stream>>>(x, xb);
  binA_k<<<N_EDGES / EBA, 256, 0, stream>>>(row, col, bcnt, pairs);
  binB_k<<<NBUCK, 512, 0, stream>>>(pairs, bcnt, cursors, csr_src);

  // ---- layer 1: TLP gather -> dense MFMA transform ----
  gather1_k<<<N_NODES / 16, 256, 0, stream>>>(xb, cursors, csr_src, xm);
  mm12_k<<<N_NODES / NB1, 512, 0, stream>>>(xm, W1t, b1, W2t, g);

  // ---- layer 2: TLP gather -> head ----
  gather2_k<<<N_NODES / 16, 256, 0, stream>>>(g, cursors, csr_src, b2, hm);
  head_k<<<N_NODES / NBH3, 256, 0, stream>>>(hm, W3, b3, out);
}

// Round 18
// 153.806 us; speedup vs baseline: 1.0848x; 1.0848x over previous
//
#include <hip/hip_runtime.h>

#define N_NODES 100000
#define N_EDGES 1600000
#define IN_F 64
#define HID 128
#define HID2 64
#define NCLS 10

// fixed-stride padded CSR: 64 slots per node (max Poisson-16 degree ~45)
#define SEG 64

// two-level binning: 256 sub-buckets of 391 nodes (100KB csr window each)
#define NBUCK 256
#define SUBR 391                       // ceil(100000/256)
#define CAP2 7000                      // mean 6250, ~9.5 sigma margin
#define EBA 6250                       // edges per binA block (256 blocks)

typedef __attribute__((ext_vector_type(8))) short bfrag;
typedef __attribute__((ext_vector_type(4))) float f32x4;

// ---- RNE float->bf16 ----
__device__ __forceinline__ unsigned short bf_rne(float f) {
  unsigned int u = __float_as_uint(f);
  u += 0x7fffu + ((u >> 16) & 1u);
  return (unsigned short)(u >> 16);
}

// ---------------- cast x -> bf16 (8 floats / thread) ----------------
__global__ __launch_bounds__(256) void cast_k(const float* __restrict__ x,
                                              unsigned short* __restrict__ xb) {
  int i = blockIdx.x * blockDim.x + threadIdx.x;   // 8-float unit
  const float4* xf4 = (const float4*)x;
  float4 a = xf4[2 * i];
  float4 b = xf4[2 * i + 1];
  ushort4 o0, o1;
  o0.x = bf_rne(a.x); o0.y = bf_rne(a.y); o0.z = bf_rne(a.z); o0.w = bf_rne(a.w);
  o1.x = bf_rne(b.x); o1.y = bf_rne(b.y); o1.z = bf_rne(b.z); o1.w = bf_rne(b.w);
  ushort4* ob = (ushort4*)xb;
  ob[2 * i] = o0;
  ob[2 * i + 1] = o1;
}

// ------- W1/W2 -> bf16 transposed [out][k] (once); also zeroes bcnt -------
__global__ __launch_bounds__(256) void wtrans_k(const float* __restrict__ W1,
                                                const float* __restrict__ W2,
                                                unsigned short* __restrict__ W1t,
                                                unsigned short* __restrict__ W2t,
                                                int* __restrict__ bcnt) {
  int i = blockIdx.x * 256 + threadIdx.x;          // 0 .. 16383
  if (blockIdx.x == 0) bcnt[threadIdx.x] = 0;      // NBUCK == 256
  if (i < IN_F * HID) {                            // W1t[j][k] = W1[k][j]
    int j = i >> 6, k = i & 63;                    // j<128, k<64
    W1t[i] = bf_rne(W1[k * HID + j]);
  } else {
    int i2 = i - IN_F * HID;                       // W2t[j][k] = W2[k][j]
    int j = i2 >> 7, k = i2 & 127;                 // j<64, k<128
    W2t[i2] = bf_rne(W2[k * HID2 + j]);
  }
}

// ---- binA: bin edges into 256 buckets as packed (local<<17|src) u32 ----
// 256 blocks (EBA=6250): 65K global atomics total (R17's 1000 blocks =
// 256K atomics -> 41us; this config measured ~13us in R12-era).
__global__ __launch_bounds__(256) void binA_k(const int* __restrict__ row,
                                              const int* __restrict__ col,
                                              int* __restrict__ bcnt,
                                              unsigned int* __restrict__ pairs) {
  __shared__ int hcnt[NBUCK];
  __shared__ int hbase[NBUCK];
  int t = threadIdx.x;
  hcnt[t] = 0;
  __syncthreads();
  int e0 = blockIdx.x * EBA;
  int e1 = e0 + EBA;
  for (int e = e0 + t; e < e1; e += 256) {
    int b = col[e] / SUBR;
    atomicAdd(&hcnt[b], 1);
  }
  __syncthreads();
  hbase[t] = atomicAdd(&bcnt[t], hcnt[t]);
  hcnt[t] = 0;
  __syncthreads();
  for (int e = e0 + t; e < e1; e += 256) {
    int dst = col[e];
    int src = row[e];
    int b = dst / SUBR;
    int pos = hbase[b] + atomicAdd(&hcnt[b], 1);
    pairs[(size_t)b * CAP2 + pos] =
        ((unsigned)(dst - b * SUBR) << 17) | (unsigned)src;
  }
}

// ---- binB: one block per bucket; LDS cursors; 100KB private csr window ----
// Zero-fills slots d..cons (cons = 32 or ceil16(d)) so the gather can read
// the first 32 slots (and any tail units) unconditionally.
__global__ __launch_bounds__(512) void binB_k(const unsigned int* __restrict__ pairs,
                                              const int* __restrict__ bcnt,
                                              int* __restrict__ cursors,
                                              int* __restrict__ csr_src) {
  __shared__ int cur[SUBR];
  int b = blockIdx.x;
  int t = threadIdx.x;
  int lo = b * SUBR;
  for (int i = t; i < SUBR; i += 512) cur[i] = 0;
  __syncthreads();
  int cnt = bcnt[b];
  const unsigned int* bp = pairs + (size_t)b * CAP2;
  for (int i = t; i < cnt; i += 512) {
    unsigned w = bp[i];
    int local = w >> 17;
    int src = (int)(w & 0x1ffffu);
    int pos = atomicAdd(&cur[local], 1);
    if (pos < SEG) csr_src[(size_t)(lo + local) * SEG + pos] = src;
  }
  __syncthreads();
  for (int i = t; i < SUBR; i += 512) {
    int n = lo + i;
    if (n < N_NODES) {
      int d = cur[i];
      if (d > SEG) d = SEG;
      cursors[n] = n * SEG + d;
      int cons = d <= 32 ? 32 : ((d + 15) & ~15);
      for (int q = d; q < cons; q++) csr_src[(size_t)n * SEG + q] = 0;
    }
  }
}

// ---------- per-node bf16 gather (TLP version: no LDS, no barriers) ----------
// Row = 64 bf16 = 128 B. Lane = eg(0..3 edge-subgroup) x fc(0..15 chunk).
// Slots [0,32) always initialized (binB); pad slots = row0, subtracted.
// After xor-reduce 16/32 ALL lanes hold the node's sum for chunk fc.
__device__ __forceinline__ float4 gather_node(const uint2* __restrict__ vb,
                                              const int4* __restrict__ csr4,
                                              int n, int d, int eg, int fc,
                                              float zx, float zy, float zz,
                                              float zw) {
  float ax = 0.f, ay = 0.f, az = 0.f, aw = 0.f;
  int s4 = n * 16;                           // 16 int4 units per SEG
  int4 ia = csr4[s4 + eg];
  int4 ib = csr4[s4 + 4 + eg];
  uint2 r0 = vb[(size_t)(unsigned)ia.x * 16 + fc];
  uint2 r1 = vb[(size_t)(unsigned)ia.y * 16 + fc];
  uint2 r2 = vb[(size_t)(unsigned)ia.z * 16 + fc];
  uint2 r3 = vb[(size_t)(unsigned)ia.w * 16 + fc];
  uint2 r4 = vb[(size_t)(unsigned)ib.x * 16 + fc];
  uint2 r5 = vb[(size_t)(unsigned)ib.y * 16 + fc];
  uint2 r6 = vb[(size_t)(unsigned)ib.z * 16 + fc];
  uint2 r7 = vb[(size_t)(unsigned)ib.w * 16 + fc];
#define ACC1(r)                                                     \
  {                                                                 \
    ax += __uint_as_float((r).x << 16);                             \
    ay += __uint_as_float((r).x & 0xffff0000u);                     \
    az += __uint_as_float((r).y << 16);                             \
    aw += __uint_as_float((r).y & 0xffff0000u);                     \
  }
  ACC1(r0) ACC1(r1) ACC1(r2) ACC1(r3) ACC1(r4) ACC1(r5) ACC1(r6) ACC1(r7)
  int cons = 32;
  if (d > 32) {                              // rare tail (P ~ 2e-4)
    cons = (d + 15) & ~15;
    for (int p = n * SEG + 32; p < n * SEG + cons; p += 16) {
      int4 it = csr4[(p >> 2) + eg];
      uint2 t0 = vb[(size_t)(unsigned)it.x * 16 + fc];
      uint2 t1 = vb[(size_t)(unsigned)it.y * 16 + fc];
      uint2 t2 = vb[(size_t)(unsigned)it.z * 16 + fc];
      uint2 t3 = vb[(size_t)(unsigned)it.w * 16 + fc];
      ACC1(t0) ACC1(t1) ACC1(t2) ACC1(t3)
    }
  }
#undef ACC1
  ax += __shfl_xor(ax, 16); ay += __shfl_xor(ay, 16);
  az += __shfl_xor(az, 16); aw += __shfl_xor(aw, 16);
  ax += __shfl_xor(ax, 32); ay += __shfl_xor(ay, 32);
  az += __shfl_xor(az, 32); aw += __shfl_xor(aw, 32);
  float pc = (float)(cons - d);
  return make_float4(ax - pc * zx, ay - pc * zy, az - pc * zz, aw - pc * zw);
}

// ---------- gather1: xm[n] = bf16(mean of xb rows) ----------
// 256 thr = 4 waves x 4 nodes; no LDS/barriers -> 8 waves/SIMD residency.
__global__ __launch_bounds__(256) void gather1_k(
    const unsigned short* __restrict__ xb, const int* __restrict__ cursors,
    const int* __restrict__ csr_src, unsigned short* __restrict__ xm) {
  int t = threadIdx.x;
  int lane = t & 63;
  int eg = lane >> 4;
  int fc = lane & 15;
  int n0 = (blockIdx.x * 4 + (t >> 6)) * 4;
  const uint2* vb = (const uint2*)xb;
  const int4* csr4 = (const int4*)csr_src;
  uint2 z = vb[fc];
  float zx = __uint_as_float(z.x << 16);
  float zy = __uint_as_float(z.x & 0xffff0000u);
  float zz = __uint_as_float(z.y << 16);
  float zw = __uint_as_float(z.y & 0xffff0000u);
  for (int i = 0; i < 4; i++) {
    int n = n0 + i;
    int d = cursors[n] - n * SEG;
    float4 a = gather_node(vb, csr4, n, d, eg, fc, zx, zy, zz, zw);
    if (eg == 0) {
      float inv = 1.0f / (d < 1 ? 1.0f : (float)d);
      ushort4 o;
      o.x = bf_rne(a.x * inv); o.y = bf_rne(a.y * inv);
      o.z = bf_rne(a.z * inv); o.w = bf_rne(a.w * inv);
      *(ushort4*)&xm[(size_t)n * IN_F + fc * 4] = o;
    }
  }
}

// ---------- gather2: hm[n] = bf16(relu(mean of g rows + b2)) ----------
__global__ __launch_bounds__(256) void gather2_k(
    const unsigned short* __restrict__ g, const int* __restrict__ cursors,
    const int* __restrict__ csr_src, const float* __restrict__ b2,
    unsigned short* __restrict__ hm) {
  int t = threadIdx.x;
  int lane = t & 63;
  int eg = lane >> 4;
  int fc = lane & 15;
  int n0 = (blockIdx.x * 4 + (t >> 6)) * 4;
  const uint2* vb = (const uint2*)g;
  const int4* csr4 = (const int4*)csr_src;
  uint2 z = vb[fc];
  float zx = __uint_as_float(z.x << 16);
  float zy = __uint_as_float(z.x & 0xffff0000u);
  float zz = __uint_as_float(z.y << 16);
  float zw = __uint_as_float(z.y & 0xffff0000u);
  const float4* b2f4 = (const float4*)b2;
  float4 bb = b2f4[fc];
  for (int i = 0; i < 4; i++) {
    int n = n0 + i;
    int d = cursors[n] - n * SEG;
    float4 a = gather_node(vb, csr4, n, d, eg, fc, zx, zy, zz, zw);
    if (eg == 0) {
      float inv = 1.0f / (d < 1 ? 1.0f : (float)d);
      float vx = a.x * inv + bb.x;
      float vy = a.y * inv + bb.y;
      float vz = a.z * inv + bb.z;
      float vw = a.w * inv + bb.w;
      ushort4 o;
      o.x = bf_rne(vx > 0.0f ? vx : 0.0f);
      o.y = bf_rne(vy > 0.0f ? vy : 0.0f);
      o.z = bf_rne(vz > 0.0f ? vz : 0.0f);
      o.w = bf_rne(vw > 0.0f ? vw : 0.0f);
      *(ushort4*)&hm[(size_t)n * HID2 + fc * 4] = o;
    }
  }
}

// ---------- mm12: dense MFMA, g = bf16(relu(xm@W1+b1) @ W2) ----------
// 32 nodes/block, 512 thr (8 waves); xm tile staged coalesced into LDS.
#define NB1 32
#define XS_S 72
#define HS_S 136
__global__ __launch_bounds__(512) void mm12_k(
    const unsigned short* __restrict__ xm, const unsigned short* __restrict__ W1t,
    const float* __restrict__ b1, const unsigned short* __restrict__ W2t,
    unsigned short* __restrict__ g) {
  __shared__ unsigned short xsb[NB1 * XS_S];    // 4.5 KB
  __shared__ unsigned short hsb[NB1 * HS_S];    // 8.5 KB
  int t = threadIdx.x;
  int node0 = blockIdx.x * NB1;
  // stage xm tile: 32 rows x 16 ushort4 units = 512 units, one per thread
  {
    int r = t >> 4, u = t & 15;
    *(ushort4*)&xsb[r * XS_S + u * 4] =
        ((const ushort4*)xm)[(size_t)(node0 + r) * (IN_F / 4) + u];
  }
  __syncthreads();
  int wave = t >> 6;
  int lane = t & 63;
  int lr = lane & 15;
  int kb = lane >> 4;
  // ---- mm1 (MFMA): hsb = relu(xsb @ W1 + b1); wave w -> col-tile c=w ----
  {
    int col = wave * 16 + lr;
    bfrag wf0 = *(const bfrag*)&W1t[col * IN_F + kb * 8];
    bfrag wf1 = *(const bfrag*)&W1t[col * IN_F + 32 + kb * 8];
    float bb = b1[col];
#pragma unroll
    for (int m = 0; m < 2; m++) {
      f32x4 acc = {0.f, 0.f, 0.f, 0.f};
      bfrag a0 = *(const bfrag*)&xsb[(m * 16 + lr) * XS_S + kb * 8];
      bfrag a1 = *(const bfrag*)&xsb[(m * 16 + lr) * XS_S + 32 + kb * 8];
      acc = __builtin_amdgcn_mfma_f32_16x16x32_bf16(a0, wf0, acc, 0, 0, 0);
      acc = __builtin_amdgcn_mfma_f32_16x16x32_bf16(a1, wf1, acc, 0, 0, 0);
#pragma unroll
      for (int q = 0; q < 4; q++) {
        int r = m * 16 + kb * 4 + q;
        float v = acc[q] + bb;
        hsb[r * HS_S + col] = bf_rne(v > 0.0f ? v : 0.0f);
      }
    }
  }
  __syncthreads();
  // ---- mm2 (MFMA): g = bf16(hsb @ W2); wave w -> (m=w>>2, c=w&3) ----
  {
    int m = wave >> 2;
    int col = (wave & 3) * 16 + lr;
    f32x4 acc = {0.f, 0.f, 0.f, 0.f};
#pragma unroll
    for (int s = 0; s < 4; s++) {
      bfrag af = *(const bfrag*)&hsb[(m * 16 + lr) * HS_S + s * 32 + kb * 8];
      bfrag bf = *(const bfrag*)&W2t[col * HID + s * 32 + kb * 8];
      acc = __builtin_amdgcn_mfma_f32_16x16x32_bf16(af, bf, acc, 0, 0, 0);
    }
#pragma unroll
    for (int q = 0; q < 4; q++) {
      int r = m * 16 + kb * 4 + q;
      g[(size_t)(node0 + r) * HID2 + col] = bf_rne(acc[q]);
    }
  }
}

// ---------- head: out = hm @ W3 + b3 ----------
// 25 nodes/block, 256 thr; hm tile -> LDS fp32; 250 thr compute 10 cls each.
#define NBH3 25
__global__ __launch_bounds__(256) void head_k(
    const unsigned short* __restrict__ hm, const float* __restrict__ W3,
    const float* __restrict__ b3, float* __restrict__ out) {
  __shared__ float W3l[HID2 * NCLS];       // 2.5 KB
  __shared__ float hsl[NBH3][HID2 + 4];    // 6.8 KB
  int t = threadIdx.x;
  for (int i = t; i < HID2 * NCLS; i += 256) W3l[i] = W3[i];
  int node0 = blockIdx.x * NBH3;
  for (int u = t; u < NBH3 * (HID2 / 4); u += 256) {
    int r = u >> 4, c = u & 15;
    ushort4 v = ((const ushort4*)hm)[(size_t)(node0 + r) * (HID2 / 4) + c];
    hsl[r][c * 4 + 0] = __uint_as_float((unsigned)v.x << 16);
    hsl[r][c * 4 + 1] = __uint_as_float((unsigned)v.y << 16);
    hsl[r][c * 4 + 2] = __uint_as_float((unsigned)v.z << 16);
    hsl[r][c * 4 + 3] = __uint_as_float((unsigned)v.w << 16);
  }
  __syncthreads();
  if (t < NBH3 * NCLS) {
    int n = t / NCLS;
    int c = t - n * NCLS;
    float a = b3[c];
    for (int k = 0; k < HID2; k++) a += hsl[n][k] * W3l[k * NCLS + c];
    out[(size_t)(node0 + n) * NCLS + c] = a;
  }
}

extern "C" void kernel_launch(void* const* d_in, const int* in_sizes, int n_in,
                              void* d_out, int out_size, void* d_ws, size_t ws_size,
                              hipStream_t stream) {
  const float* x  = (const float*)d_in[0];
  const int*   ei = (const int*)d_in[1];
  const int*   row = ei;
  const int*   col = ei + N_EDGES;
  const float* W1 = (const float*)d_in[3];
  const float* b1 = (const float*)d_in[4];
  const float* W2 = (const float*)d_in[5];
  const float* b2 = (const float*)d_in[6];
  const float* W3 = (const float*)d_in[7];
  const float* b3 = (const float*)d_in[8];
  float* out = (float*)d_out;

  char* ws = (char*)d_ws;
  int*            cursors = (int*)ws;                            // 400 KB
  int*            bcnt    = (int*)(ws + (512 << 10));            // 1 KB
  unsigned short* W1t     = (unsigned short*)(ws + (520 << 10)); // 16 KB
  unsigned short* W2t     = (unsigned short*)(ws + (552 << 10)); // 16 KB
  int*            csr_src = (int*)(ws + (1 << 20));              // 25.6 MB
  unsigned int*   pairs   = (unsigned int*)(ws + (28 << 20));    // 7.2 MB
  unsigned short* xb      = (unsigned short*)(ws + (36 << 20));  // 12.8 MB
  unsigned short* g       = (unsigned short*)(ws + (49 << 20));  // 12.8 MB
  unsigned short* xm      = (unsigned short*)(ws + (62 << 20));  // 12.8 MB
  unsigned short* hm      = xm;  // aliased: xm dead after mm12_k, hm written after

  // ---- prep: W transpose (+bcnt zero) + bf16 cast + binned CSR build ----
  wtrans_k<<<(IN_F * HID + HID * HID2) / 256, 256, 0, stream>>>(W1, W2, W1t, W2t, bcnt);
  cast_k<<<N_NODES * IN_F / 8 / 256, 256, 0, stream>>>(x, xb);
  binA_k<<<N_EDGES / EBA, 256, 0, stream>>>(row, col, bcnt, pairs);
  binB_k<<<NBUCK, 512, 0, stream>>>(pairs, bcnt, cursors, csr_src);

  // ---- layer 1: TLP gather -> dense MFMA transform ----
  gather1_k<<<N_NODES / 16, 256, 0, stream>>>(xb, cursors, csr_src, xm);
  mm12_k<<<N_NODES / NB1, 512, 0, stream>>>(xm, W1t, b1, W2t, g);

  // ---- layer 2: TLP gather -> head ----
  gather2_k<<<N_NODES / 16, 256, 0, stream>>>(g, cursors, csr_src, b2, hm);
  head_k<<<N_NODES / NBH3, 256, 0, stream>>>(hm, W3, b3, out);
}